// Round 1
// baseline (773.457 us; speedup 1.0000x reference)
//
#include <hip/hip_runtime.h>

// Retention, B=4 S=4096 H=1024, gamma=0.96875.
// out[b,i,h] = sum_{j<=i} gamma^(i-j) * (q_i . k_j) * v[j,h]
// q = x Wq^T + bq ; k = x Wk^T + bk ; v = x Wv^T
//
// Stage 0: cvt x, Wq, Wk, Wv to bf16 (ws).
// Stage 1: 3x m97-style bf16 MFMA GEMMs -> qb, kb (row-major bf16), vt (transposed [b][h][s] bf16).
// Stage 2: banded flash-retention, window 512 (gamma^513/(1-gamma) contribution ~7e-5, negligible
//          vs bf16-floor threshold). 16 queries/block, Q in LDS, K/Vt frags direct from global,
//          P (16x64) through LDS for C-layout -> A-layout transform.

typedef __attribute__((ext_vector_type(8))) short short8;   // 8 bf16 = 4 VGPRs
typedef __attribute__((ext_vector_type(4))) float floatx4;  // MFMA 16x16 C/D

#define MFMA(a, b, c) __builtin_amdgcn_mfma_f32_16x16x32_bf16((a), (b), (c), 0, 0, 0)

#define B_SZ   4
#define S_LEN  4096
#define H_DIM  1024
#define NROWS  (B_SZ * S_LEN)          // 16384
#define LOG2G  (-0.045803690f)         // log2(0.96875) = log2(31) - 5
#define WND    512                     // decay window (key tiles of 64)

__device__ __forceinline__ unsigned short f32_to_bf16_rn(float f) {
    unsigned int u = __float_as_uint(f);
    u += 0x7FFFu + ((u >> 16) & 1u);   // round-to-nearest-even
    return (unsigned short)(u >> 16);
}

#define GLOAD_LDS16(gptr, lptr)                                                        \
    __builtin_amdgcn_global_load_lds((__attribute__((address_space(1))) void*)(gptr),  \
                                     (__attribute__((address_space(3))) void*)(lptr),  \
                                     16, 0, 0)

// ---------------------------------------------------------------- cvt f32->bf16
__global__ __launch_bounds__(256) void cvt_bf16(const float* __restrict__ src,
                                                unsigned short* __restrict__ dst, int n4) {
    int i = blockIdx.x * 256 + threadIdx.x;
    if (i >= n4) return;
    float4 v = ((const float4*)src)[i];
    ushort4 o;
    o.x = f32_to_bf16_rn(v.x);
    o.y = f32_to_bf16_rn(v.y);
    o.z = f32_to_bf16_rn(v.z);
    o.w = f32_to_bf16_rn(v.w);
    ((ushort4*)dst)[i] = o;
}

// ---------------------------------------------------------------- QKV projection GEMM
// C[n,o] = sum_h A[n,h] * W[o,h] (+ bias[o]).  A=[16384][1024] bf16, W=[1024][1024] bf16.
// 128x128 tile, BK=32, 256 thr / 4 waves (2x2 of 64x64), global_load_lds width-16 staging.
// transposed==0: out[n*1024+o] ; transposed==1: out[((n>>12)*1024+o)*4096 + (n&4095)]  (V^T)
__global__ __launch_bounds__(256) void qkv_gemm(const unsigned short* __restrict__ A,
                                                const unsigned short* __restrict__ W,
                                                const float* __restrict__ bias,
                                                unsigned short* __restrict__ out,
                                                int transposed) {
    __shared__ unsigned short As[128 * 32];   // 8 KB, no padding (global_load_lds constraint)
    __shared__ unsigned short Bs[128 * 32];

    const int tid  = threadIdx.x;
    const int lane = tid & 63;
    const int w    = tid >> 6;
    const int wm   = w >> 1, wn = w & 1;
    const int rowBase = blockIdx.y * 128;
    const int colBase = blockIdx.x * 128;
    const int l15 = lane & 15;
    const int q8  = (lane >> 4) * 8;

    floatx4 acc[4][4];
#pragma unroll
    for (int i = 0; i < 4; ++i)
#pragma unroll
        for (int j = 0; j < 4; ++j) acc[i][j] = (floatx4)0.0f;

    for (int kt = 0; kt < H_DIM / 32; ++kt) {
        __syncthreads();   // previous iter's ds_reads done before overwriting LDS
        const int k0 = kt * 32;
#pragma unroll
        for (int p = 0; p < 2; ++p) {
            const int c = p * 256 + tid;            // 16B chunk id, 512 chunks per tile
            // global: row = c>>2 (4 chunks/row of 64B), chunk-in-row = c&3
            const unsigned short* gA = A + (size_t)(rowBase + (c >> 2)) * H_DIM + k0 + (c & 3) * 8;
            const unsigned short* gW = W + (size_t)(colBase + (c >> 2)) * H_DIM + k0 + (c & 3) * 8;
            // LDS dest: wave-uniform base + lane*16
            char* lA = (char*)As + (size_t)(p * 256 + w * 64) * 16;
            char* lB = (char*)Bs + (size_t)(p * 256 + w * 64) * 16;
            GLOAD_LDS16(gA, lA);
            GLOAD_LDS16(gW, lB);
        }
        __syncthreads();   // compiler drains vmcnt(0) here

        short8 af[4], bf[4];
#pragma unroll
        for (int mt = 0; mt < 4; ++mt)
            af[mt] = *(const short8*)(As + (wm * 64 + mt * 16 + l15) * 32 + q8);
#pragma unroll
        for (int nt = 0; nt < 4; ++nt)
            bf[nt] = *(const short8*)(Bs + (wn * 64 + nt * 16 + l15) * 32 + q8);
#pragma unroll
        for (int mt = 0; mt < 4; ++mt)
#pragma unroll
            for (int nt = 0; nt < 4; ++nt)
                acc[mt][nt] = MFMA(af[mt], bf[nt], acc[mt][nt]);
    }

    // epilogue: C/D layout col=lane&15, row=(lane>>4)*4+r
    const int q4 = (lane >> 4) * 4;
#pragma unroll
    for (int nt = 0; nt < 4; ++nt) {
        const int o = colBase + wn * 64 + nt * 16 + l15;
        const float bv = bias ? bias[o] : 0.0f;
#pragma unroll
        for (int mt = 0; mt < 4; ++mt) {
#pragma unroll
            for (int r = 0; r < 4; ++r) {
                const int n = rowBase + wm * 64 + mt * 16 + q4 + r;
                const unsigned short hv = f32_to_bf16_rn(acc[mt][nt][r] + bv);
                if (!transposed)
                    out[(size_t)n * H_DIM + o] = hv;
                else
                    out[((size_t)(n >> 12) * H_DIM + o) * S_LEN + (n & (S_LEN - 1))] = hv;
            }
        }
    }
}

// ---------------------------------------------------------------- banded retention
// grid (S/16, B), 256 thr / 4 waves. Wave w owns output columns [w*256, w*256+256).
// Per key tile of 64: phase1 S=Q K^T (K frags direct from global), decay+mask,
// P through LDS (bf16), phase2 O += P V (V^T frags direct from global).
__global__ __launch_bounds__(256) void retention_attn(const unsigned short* __restrict__ qb,
                                                      const unsigned short* __restrict__ kb,
                                                      const unsigned short* __restrict__ vt,
                                                      float* __restrict__ out) {
    __shared__ unsigned short Qs[16 * 1032];   // +8 pad: row stride 2064B -> 2-way banks (free)
    __shared__ unsigned short Ps[16 * 72];     // +8 pad

    const int tid  = threadIdx.x;
    const int lane = tid & 63;
    const int w    = tid >> 6;
    const int q0   = blockIdx.x * 16;
    const int b    = blockIdx.y;
    const int l15  = lane & 15;
    const int q8   = (lane >> 4) * 8;
    const int q4   = (lane >> 4) * 4;

    // load Q tile (16 x 1024) into LDS, uint4 chunks, coalesced
    const unsigned short* qrow = qb + (size_t)(b * S_LEN + q0) * H_DIM;
#pragma unroll
    for (int i = 0; i < 8; ++i) {
        const int c    = i * 256 + tid;        // 2048 chunks of 8 elems
        const int r    = c >> 7;               // 128 chunks per row
        const int col8 = (c & 127) * 8;
        *(uint4*)(Qs + r * 1032 + col8) = *(const uint4*)(qrow + r * H_DIM + col8);
    }

    floatx4 acc[16];
#pragma unroll
    for (int i = 0; i < 16; ++i) acc[i] = (floatx4)0.0f;

    __syncthreads();

    const int kthi = q0 >> 6;
    const int ktlo = (q0 > WND) ? ((q0 - WND) >> 6) : 0;

    for (int kt = ktlo; kt <= kthi; ++kt) {
        // ---- phase 1: S[16 x 16-per-wave] = Q . K^T over H=1024
        floatx4 s0 = (floatx4)0.0f, s1 = (floatx4)0.0f;   // 2 accs for MFMA ILP
        const int krow = kt * 64 + w * 16 + l15;
        const unsigned short* kptr = kb + (size_t)(b * S_LEN + krow) * H_DIM + q8;
        const unsigned short* qpt  = Qs + l15 * 1032 + q8;
#pragma unroll 4
        for (int hc = 0; hc < H_DIM; hc += 64) {
            short8 a0 = *(const short8*)(qpt + hc);
            short8 a1 = *(const short8*)(qpt + hc + 32);
            short8 b0 = *(const short8*)(kptr + hc);
            short8 b1 = *(const short8*)(kptr + hc + 32);
            s0 = MFMA(a0, b0, s0);
            s1 = MFMA(a1, b1, s1);
        }

        // ---- decay + causal mask, P -> LDS (bf16)
        __syncthreads();   // all waves done reading Ps from previous iteration
#pragma unroll
        for (int r = 0; r < 4; ++r) {
            const int i_ = q0 + q4 + r;
            const int j_ = kt * 64 + w * 16 + l15;
            const int d  = i_ - j_;
            const float sv = s0[r] + s1[r];
            const float pv = (d >= 0) ? sv * exp2f((float)d * LOG2G) : 0.0f;
            Ps[(q4 + r) * 72 + w * 16 + l15] = f32_to_bf16_rn(pv);
        }
        __syncthreads();

        // ---- phase 2: O[16 x 256-per-wave] += P . V  (V^T frags from global)
        const unsigned short* vbase = vt + (size_t)(b * H_DIM + w * 256) * S_LEN + kt * 64;
#pragma unroll
        for (int ks = 0; ks < 2; ++ks) {
            short8 pf = *(const short8*)(Ps + l15 * 72 + ks * 32 + q8);
#pragma unroll
            for (int nt = 0; nt < 16; ++nt) {
                short8 vf = *(const short8*)(vbase + (size_t)(nt * 16 + l15) * S_LEN + ks * 32 + q8);
                acc[nt] = MFMA(pf, vf, acc[nt]);
            }
        }
    }

    // ---- store O (f32): row=(lane>>4)*4+r, col=lane&15 within each 16-wide tile
    float* orow = out + (size_t)(b * S_LEN + q0) * H_DIM + (size_t)w * 256;
#pragma unroll
    for (int nt = 0; nt < 16; ++nt) {
#pragma unroll
        for (int r = 0; r < 4; ++r) {
            orow[(size_t)(q4 + r) * H_DIM + nt * 16 + l15] = acc[nt][r];
        }
    }
}

// ---------------------------------------------------------------- launcher
extern "C" void kernel_launch(void* const* d_in, const int* in_sizes, int n_in,
                              void* d_out, int out_size, void* d_ws, size_t ws_size,
                              hipStream_t stream) {
    (void)in_sizes; (void)n_in; (void)out_size; (void)ws_size;

    const float* x  = (const float*)d_in[0];
    const float* Wq = (const float*)d_in[1];
    const float* bq = (const float*)d_in[2];
    const float* Wk = (const float*)d_in[3];
    const float* bk = (const float*)d_in[4];
    const float* Wv = (const float*)d_in[5];
    float* out = (float*)d_out;

    // workspace layout (bf16 elems): xb | qb | kb | vt | wqb | wkb | wvb  = ~134 MB
    unsigned short* xb  = (unsigned short*)d_ws;
    unsigned short* qbf = xb  + (size_t)NROWS * H_DIM;
    unsigned short* kbf = qbf + (size_t)NROWS * H_DIM;
    unsigned short* vtb = kbf + (size_t)NROWS * H_DIM;
    unsigned short* wqb = vtb + (size_t)NROWS * H_DIM;
    unsigned short* wkb = wqb + (size_t)H_DIM * H_DIM;
    unsigned short* wvb = wkb + (size_t)H_DIM * H_DIM;

    cvt_bf16<<<(NROWS * H_DIM / 4 + 255) / 256, 256, 0, stream>>>(x, xb, NROWS * H_DIM / 4);
    cvt_bf16<<<(H_DIM * H_DIM / 4 + 255) / 256, 256, 0, stream>>>(Wq, wqb, H_DIM * H_DIM / 4);
    cvt_bf16<<<(H_DIM * H_DIM / 4 + 255) / 256, 256, 0, stream>>>(Wk, wkb, H_DIM * H_DIM / 4);
    cvt_bf16<<<(H_DIM * H_DIM / 4 + 255) / 256, 256, 0, stream>>>(Wv, wvb, H_DIM * H_DIM / 4);

    dim3 ggrid(H_DIM / 128, NROWS / 128);   // (8, 128)
    qkv_gemm<<<ggrid, 256, 0, stream>>>(xb, wqb, bq, qbf, 0);
    qkv_gemm<<<ggrid, 256, 0, stream>>>(xb, wkb, bk, kbf, 0);
    qkv_gemm<<<ggrid, 256, 0, stream>>>(xb, wvb, nullptr, vtb, 1);

    dim3 agrid(S_LEN / 16, B_SZ);           // (256, 4)
    retention_attn<<<agrid, 256, 0, stream>>>(qbf, kbf, vtb, out);
}

// Round 2
// 523.207 us; speedup vs baseline: 1.4783x; 1.4783x over previous
//
#include <hip/hip_runtime.h>

// Retention, B=4 S=4096 H=1024, gamma=0.96875.
// out[b,i,h] = sum_{j<=i} gamma^(i-j) * (q_i . k_j) * v[j,h]
//
// Stage 0: cvt x, Wq, Wk, Wv to bf16 (ws).
// Stage 1: 3x m97-style bf16 MFMA GEMMs -> qb, kb (row-major), vt (transposed [b][h][s]).
// Stage 2: banded flash-retention, window 512 (truncation error ~1e-5 << bf16 threshold).
//          M=64 queries/block, 512 thr (8 waves), Q tile LDS-resident (132 KB),
//          K/Vt fragments streamed from global, P (64x64) through padded LDS.

typedef __attribute__((ext_vector_type(8))) short short8;   // 8 bf16 = 4 VGPRs
typedef __attribute__((ext_vector_type(4))) float floatx4;  // MFMA 16x16 C/D

#define MFMA(a, b, c) __builtin_amdgcn_mfma_f32_16x16x32_bf16((a), (b), (c), 0, 0, 0)

#define B_SZ   4
#define S_LEN  4096
#define H_DIM  1024
#define NROWS  (B_SZ * S_LEN)          // 16384
#define LOG2G  (-0.045803690f)         // log2(0.96875)

__device__ __forceinline__ unsigned short f32_to_bf16_rn(float f) {
    unsigned int u = __float_as_uint(f);
    u += 0x7FFFu + ((u >> 16) & 1u);   // round-to-nearest-even
    return (unsigned short)(u >> 16);
}

#define GLOAD_LDS16(gptr, lptr)                                                        \
    __builtin_amdgcn_global_load_lds((__attribute__((address_space(1))) void*)(gptr),  \
                                     (__attribute__((address_space(3))) void*)(lptr),  \
                                     16, 0, 0)

// ---------------------------------------------------------------- cvt f32->bf16
__global__ __launch_bounds__(256) void cvt_bf16(const float* __restrict__ src,
                                                unsigned short* __restrict__ dst, int n4) {
    int i = blockIdx.x * 256 + threadIdx.x;
    if (i >= n4) return;
    float4 v = ((const float4*)src)[i];
    ushort4 o;
    o.x = f32_to_bf16_rn(v.x);
    o.y = f32_to_bf16_rn(v.y);
    o.z = f32_to_bf16_rn(v.z);
    o.w = f32_to_bf16_rn(v.w);
    ((ushort4*)dst)[i] = o;
}

// ---------------------------------------------------------------- QKV projection GEMM
// C[n,o] = sum_h A[n,h] * W[o,h] (+ bias[o]).  128x128 tile, BK=32, 256 thr,
// global_load_lds width-16 staging.  transposed -> V^T layout [b][h][s].
__global__ __launch_bounds__(256) void qkv_gemm(const unsigned short* __restrict__ A,
                                                const unsigned short* __restrict__ W,
                                                const float* __restrict__ bias,
                                                unsigned short* __restrict__ out,
                                                int transposed) {
    __shared__ unsigned short As[128 * 32];
    __shared__ unsigned short Bs[128 * 32];

    const int tid  = threadIdx.x;
    const int lane = tid & 63;
    const int w    = tid >> 6;
    const int wm   = w >> 1, wn = w & 1;
    const int rowBase = blockIdx.y * 128;
    const int colBase = blockIdx.x * 128;
    const int l15 = lane & 15;
    const int q8  = (lane >> 4) * 8;

    floatx4 acc[4][4];
#pragma unroll
    for (int i = 0; i < 4; ++i)
#pragma unroll
        for (int j = 0; j < 4; ++j) acc[i][j] = (floatx4)0.0f;

    for (int kt = 0; kt < H_DIM / 32; ++kt) {
        __syncthreads();
        const int k0 = kt * 32;
#pragma unroll
        for (int p = 0; p < 2; ++p) {
            const int c = p * 256 + tid;
            const unsigned short* gA = A + (size_t)(rowBase + (c >> 2)) * H_DIM + k0 + (c & 3) * 8;
            const unsigned short* gW = W + (size_t)(colBase + (c >> 2)) * H_DIM + k0 + (c & 3) * 8;
            char* lA = (char*)As + (size_t)(p * 256 + w * 64) * 16;
            char* lB = (char*)Bs + (size_t)(p * 256 + w * 64) * 16;
            GLOAD_LDS16(gA, lA);
            GLOAD_LDS16(gW, lB);
        }
        __syncthreads();

        short8 af[4], bf[4];
#pragma unroll
        for (int mt = 0; mt < 4; ++mt)
            af[mt] = *(const short8*)(As + (wm * 64 + mt * 16 + l15) * 32 + q8);
#pragma unroll
        for (int nt = 0; nt < 4; ++nt)
            bf[nt] = *(const short8*)(Bs + (wn * 64 + nt * 16 + l15) * 32 + q8);
#pragma unroll
        for (int mt = 0; mt < 4; ++mt)
#pragma unroll
            for (int nt = 0; nt < 4; ++nt)
                acc[mt][nt] = MFMA(af[mt], bf[nt], acc[mt][nt]);
    }

    const int q4 = (lane >> 4) * 4;
#pragma unroll
    for (int nt = 0; nt < 4; ++nt) {
        const int o = colBase + wn * 64 + nt * 16 + l15;
        const float bv = bias ? bias[o] : 0.0f;
#pragma unroll
        for (int mt = 0; mt < 4; ++mt) {
#pragma unroll
            for (int r = 0; r < 4; ++r) {
                const int n = rowBase + wm * 64 + mt * 16 + q4 + r;
                const unsigned short hv = f32_to_bf16_rn(acc[mt][nt][r] + bv);
                if (!transposed)
                    out[(size_t)n * H_DIM + o] = hv;
                else
                    out[((size_t)(n >> 12) * H_DIM + o) * S_LEN + (n & (S_LEN - 1))] = hv;
            }
        }
    }
}

// ---------------------------------------------------------------- banded retention v2
// grid (64, B), 512 thr / 8 waves.  M=64 queries/block, window = 9 key tiles of 64.
// Phase1: wave (qg=w>>1, kh=w&1) computes S[16q x 32k] streaming K from global,
//         Q a-frags from LDS.  Decay+mask -> P (bf16) in padded LDS.
// Phase2: wave w owns 128 H-cols; O[64q x 128h] += P.V with Vt frags from global.
__global__ __launch_bounds__(512, 2) void retention_attn(const unsigned short* __restrict__ qb,
                                                         const unsigned short* __restrict__ kb,
                                                         const unsigned short* __restrict__ vt,
                                                         float* __restrict__ out) {
    __shared__ unsigned short Qs[64 * 1032];   // 132.1 KB; +8 pad -> 2-way banks (free)
    __shared__ unsigned short Ps[64 * 72];     // 9.2 KB; +8 pad

    const int tid  = threadIdx.x;
    const int lane = tid & 63;
    const int w    = tid >> 6;
    const int qg   = w >> 1;       // phase1 query group (16 rows)
    const int kh   = w & 1;        // phase1 key half (32 cols)
    const int bx   = blockIdx.x;
    const int qt   = ((bx & 7) << 3) | (bx >> 3);   // XCD swizzle: 8 adjacent qtiles / XCD
    const int q0   = qt * 64;
    const int b    = blockIdx.y;
    const int l15  = lane & 15;
    const int q8   = (lane >> 4) * 8;
    const int q4   = (lane >> 4) * 4;

    // ---- stage Q tile (64 x 1024) into padded LDS, coalesced uint4
    const unsigned short* qrow = qb + (size_t)(b * S_LEN + q0) * H_DIM;
#pragma unroll
    for (int i = 0; i < 16; ++i) {
        const int c    = i * 512 + tid;        // 8192 chunks of 8 elems
        const int r    = c >> 7;               // 128 chunks per row
        const int col8 = (c & 127) * 8;
        *(uint4*)(Qs + r * 1032 + col8) = *(const uint4*)(qrow + r * H_DIM + col8);
    }

    floatx4 acc[4][8];                         // O[64q x 128h] per wave: 128 VGPRs
#pragma unroll
    for (int i = 0; i < 4; ++i)
#pragma unroll
        for (int j = 0; j < 8; ++j) acc[i][j] = (floatx4)0.0f;

    __syncthreads();

    const int kthi = qt;
    const int ktlo = (qt >= 8) ? (qt - 8) : 0;

    for (int kt = ktlo; kt <= kthi; ++kt) {
        // ---- phase 1: S[16q x 32k] = Q . K^T over H=1024
        floatx4 s0 = (floatx4)0.0f, s1 = (floatx4)0.0f;
        const int kbase = kt * 64 + kh * 32;
        const unsigned short* k0p = kb + (size_t)(b * S_LEN + kbase + l15) * H_DIM + q8;
        const unsigned short* k1p = k0p + 16 * H_DIM;
        const unsigned short* qpt = Qs + (qg * 16 + l15) * 1032 + q8;
#pragma unroll 4
        for (int hc = 0; hc < H_DIM; hc += 32) {
            short8 a  = *(const short8*)(qpt + hc);
            short8 b0 = *(const short8*)(k0p + hc);
            short8 b1 = *(const short8*)(k1p + hc);
            s0 = MFMA(a, b0, s0);
            s1 = MFMA(a, b1, s1);
        }

        // ---- decay + causal mask, P -> LDS (bf16)
        __syncthreads();   // previous phase2 P-reads complete
#pragma unroll
        for (int r = 0; r < 4; ++r) {
            const int i_ = q0 + qg * 16 + q4 + r;
            const int d0 = i_ - (kbase + l15);
            const int d1 = d0 - 16;
            const float p0 = (d0 >= 0) ? s0[r] * exp2f((float)d0 * LOG2G) : 0.0f;
            const float p1 = (d1 >= 0) ? s1[r] * exp2f((float)d1 * LOG2G) : 0.0f;
            Ps[(qg * 16 + q4 + r) * 72 + kh * 32 + l15]      = f32_to_bf16_rn(p0);
            Ps[(qg * 16 + q4 + r) * 72 + kh * 32 + 16 + l15] = f32_to_bf16_rn(p1);
        }
        __syncthreads();

        // ---- phase 2: O[64q x 128h] += P . V  (V^T frags from global)
        const unsigned short* vbase =
            vt + (size_t)(b * H_DIM + w * 128 + l15) * S_LEN + kt * 64 + q8;
#pragma unroll
        for (int ks = 0; ks < 2; ++ks) {
            short8 pf[4];
#pragma unroll
            for (int mg = 0; mg < 4; ++mg)
                pf[mg] = *(const short8*)(Ps + (mg * 16 + l15) * 72 + ks * 32 + q8);
#pragma unroll
            for (int nt = 0; nt < 8; ++nt) {
                short8 vf = *(const short8*)(vbase + (size_t)(nt * 16) * S_LEN + ks * 32);
#pragma unroll
                for (int mg = 0; mg < 4; ++mg)
                    acc[mg][nt] = MFMA(pf[mg], vf, acc[mg][nt]);
            }
        }
    }

    // ---- store O (f32)
    float* orow = out + (size_t)(b * S_LEN + q0) * H_DIM + (size_t)w * 128;
#pragma unroll
    for (int mg = 0; mg < 4; ++mg)
#pragma unroll
        for (int nt = 0; nt < 8; ++nt)
#pragma unroll
            for (int r = 0; r < 4; ++r)
                orow[(size_t)(mg * 16 + q4 + r) * H_DIM + nt * 16 + l15] = acc[mg][nt][r];
}

// ---------------------------------------------------------------- launcher
extern "C" void kernel_launch(void* const* d_in, const int* in_sizes, int n_in,
                              void* d_out, int out_size, void* d_ws, size_t ws_size,
                              hipStream_t stream) {
    (void)in_sizes; (void)n_in; (void)out_size; (void)ws_size;

    const float* x  = (const float*)d_in[0];
    const float* Wq = (const float*)d_in[1];
    const float* bq = (const float*)d_in[2];
    const float* Wk = (const float*)d_in[3];
    const float* bk = (const float*)d_in[4];
    const float* Wv = (const float*)d_in[5];
    float* out = (float*)d_out;

    unsigned short* xb  = (unsigned short*)d_ws;
    unsigned short* qbf = xb  + (size_t)NROWS * H_DIM;
    unsigned short* kbf = qbf + (size_t)NROWS * H_DIM;
    unsigned short* vtb = kbf + (size_t)NROWS * H_DIM;
    unsigned short* wqb = vtb + (size_t)NROWS * H_DIM;
    unsigned short* wkb = wqb + (size_t)H_DIM * H_DIM;
    unsigned short* wvb = wkb + (size_t)H_DIM * H_DIM;

    cvt_bf16<<<(NROWS * H_DIM / 4 + 255) / 256, 256, 0, stream>>>(x, xb, NROWS * H_DIM / 4);
    cvt_bf16<<<(H_DIM * H_DIM / 4 + 255) / 256, 256, 0, stream>>>(Wq, wqb, H_DIM * H_DIM / 4);
    cvt_bf16<<<(H_DIM * H_DIM / 4 + 255) / 256, 256, 0, stream>>>(Wk, wkb, H_DIM * H_DIM / 4);
    cvt_bf16<<<(H_DIM * H_DIM / 4 + 255) / 256, 256, 0, stream>>>(Wv, wvb, H_DIM * H_DIM / 4);

    dim3 ggrid(H_DIM / 128, NROWS / 128);   // (8, 128)
    qkv_gemm<<<ggrid, 256, 0, stream>>>(xb, wqb, bq, qbf, 0);
    qkv_gemm<<<ggrid, 256, 0, stream>>>(xb, wkb, bk, kbf, 0);
    qkv_gemm<<<ggrid, 256, 0, stream>>>(xb, wvb, nullptr, vtb, 1);

    dim3 agrid(64, B_SZ);
    retention_attn<<<agrid, 512, 0, stream>>>(qbf, kbf, vtb, out);
}

// Round 3
// 407.362 us; speedup vs baseline: 1.8987x; 1.2844x over previous
//
#include <hip/hip_runtime.h>

// Retention, B=4 S=4096 H=1024, gamma=0.96875.
// out[b,i,:] = sum_{j<=i} gamma^(i-j) * (q_i . k_j) * v_j
//
// Pipeline (all bf16 MFMA GEMMs in the m97 128x128/BK=32/global_load_lds structure):
//   x~   = [x | 1 | 0pad]                  (16384 x 1056 bf16)
//   W~qT = [Wq^T ; bq ; 0pad]              (1152 x 1024 bf16)   (same for k)
//   P1   = W~kT . W~qT^T   = M~^T          (1152 x 1056)  [P1[o,h] = M~[h,o]]
//   G    = x~ . P1^T       = x~ M~         (16384 x 1056)
//   Vt   = (Wv . x~^T) scattered           ([b][h][s] bf16, coalesced row-major store)
//   Pb   = band(G . x~^T) * gamma^d masked (128 qtiles x 128 x 640 bf16)
//   out  = Pb . Vt^T (banded K)            (f32)
// Band = 5 key-tiles of 128 => window 512..639; truncated tail < 1e-5, way under threshold.

typedef __attribute__((ext_vector_type(8))) short short8;   // 8 bf16 = 4 VGPRs
typedef __attribute__((ext_vector_type(4))) float floatx4;  // MFMA 16x16 C/D

#define MFMA(a, b, c) __builtin_amdgcn_mfma_f32_16x16x32_bf16((a), (b), (c), 0, 0, 0)

#define B_SZ   4
#define S_LEN  4096
#define H_DIM  1024
#define NROWS  (B_SZ * S_LEN)          // 16384
#define HP     1056                    // padded H+1 (33*32)
#define WR     1152                    // padded weight rows (9*128)
#define LOG2G  (-0.045803690f)         // log2(0.96875)

__device__ __forceinline__ unsigned short f32_to_bf16_rn(float f) {
    unsigned int u = __float_as_uint(f);
    u += 0x7FFFu + ((u >> 16) & 1u);   // round-to-nearest-even
    return (unsigned short)(u >> 16);
}

#define GLOAD_LDS16(gptr, lptr)                                                        \
    __builtin_amdgcn_global_load_lds((__attribute__((address_space(1))) void*)(gptr),  \
                                     (__attribute__((address_space(3))) void*)(lptr),  \
                                     16, 0, 0)

// ---------------------------------------------------------------- cvt f32->bf16 (contiguous)
__global__ __launch_bounds__(256) void cvt_bf16(const float* __restrict__ src,
                                                unsigned short* __restrict__ dst, int n4) {
    int i = blockIdx.x * 256 + threadIdx.x;
    if (i >= n4) return;
    float4 v = ((const float4*)src)[i];
    ushort4 o;
    o.x = f32_to_bf16_rn(v.x);
    o.y = f32_to_bf16_rn(v.y);
    o.z = f32_to_bf16_rn(v.z);
    o.w = f32_to_bf16_rn(v.w);
    ((ushort4*)dst)[i] = o;
}

// ---------------------------------------------------------------- cvt x -> x~ (strided rows of 1056)
__global__ __launch_bounds__(256) void cvt_x(const float* __restrict__ src,
                                             unsigned short* __restrict__ dst) {
    int idx = blockIdx.x * 256 + threadIdx.x;     // 16384*128 chunks of 8
    int row = idx >> 7, c8 = (idx & 127) * 8;
    const float4* s = (const float4*)(src + (size_t)row * H_DIM + c8);
    float4 a = s[0], b = s[1];
    ushort4 o0, o1;
    o0.x = f32_to_bf16_rn(a.x); o0.y = f32_to_bf16_rn(a.y);
    o0.z = f32_to_bf16_rn(a.z); o0.w = f32_to_bf16_rn(a.w);
    o1.x = f32_to_bf16_rn(b.x); o1.y = f32_to_bf16_rn(b.y);
    o1.z = f32_to_bf16_rn(b.z); o1.w = f32_to_bf16_rn(b.w);
    ushort4* d = (ushort4*)(dst + (size_t)row * HP + c8);
    d[0] = o0; d[1] = o1;
}

// cols 1024..1055 of x~: 1.0 at col 1024, zeros elsewhere
__global__ __launch_bounds__(256) void fill_pad(unsigned short* __restrict__ dst) {
    int idx = blockIdx.x * 256 + threadIdx.x;     // 16384*4 chunks of 8
    int row = idx >> 2, c = idx & 3;
    uint4 v; v.x = (c == 0) ? 0x00003F80u : 0u; v.y = 0u; v.z = 0u; v.w = 0u;
    *(uint4*)(dst + (size_t)row * HP + 1024 + c * 8) = v;
}

// ---------------------------------------------------------------- W (f32) + bias -> [W^T ; bias ; 0] bf16, 1152x1024
__global__ __launch_bounds__(256) void tr_cvt(const float* __restrict__ Wsrc,
                                              const float* __restrict__ bias,
                                              unsigned short* __restrict__ dst) {
    const int tid = threadIdx.x;
    const int bx = blockIdx.x, by = blockIdx.y;
    if (by >= 32) {                                // rows 1024..1151: bias row + zeros
        if (bx != 0) return;
        const int h0 = by * 32;
#pragma unroll
        for (int i = 0; i < 128; ++i) {
            int idx = i * 256 + tid;               // 32*1024
            int r = idx >> 10, cc = idx & 1023;
            int h = h0 + r;
            float v = (h == 1024) ? bias[cc] : 0.0f;
            dst[(size_t)h * 1024 + cc] = f32_to_bf16_rn(v);
        }
        return;
    }
    __shared__ float Lt[128][33];
    const int w0 = bx * 128, h0 = by * 32;
#pragma unroll
    for (int i = 0; i < 16; ++i) {
        int idx = i * 256 + tid;                   // 128 rows x 32 cols
        int r = idx >> 5, cc = idx & 31;
        Lt[r][cc] = Wsrc[(size_t)(w0 + r) * 1024 + h0 + cc];
    }
    __syncthreads();
#pragma unroll
    for (int i = 0; i < 16; ++i) {
        int idx = i * 256 + tid;                   // 32 rows x 128 cols
        int hh = idx >> 7, ww = idx & 127;
        dst[(size_t)(h0 + hh) * 1024 + w0 + ww] = f32_to_bf16_rn(Lt[ww][hh]);
    }
}

// ---------------------------------------------------------------- generic 128x128 MFMA GEMM
// C[n,o] = sum_k A[n,k]*W[o,k].   MODE 0: bf16 row-major store (col-clip p0)
// MODE 1: Vt scatter store   MODE 2: decay epilogue -> Pb band   MODE 3: banded-K, f32 store
template <int MODE>
__global__ __launch_bounds__(256) void gemm128(const unsigned short* __restrict__ A, int lda,
                                               const unsigned short* __restrict__ W, int ldw,
                                               void* __restrict__ outp, int ldo, int K, int p0) {
    __shared__ unsigned short As[128 * 32];
    __shared__ unsigned short Bs[128 * 32];

    const int tid  = threadIdx.x;
    const int lane = tid & 63;
    const int w4   = tid >> 6;
    const int wm   = w4 >> 1, wn = w4 & 1;
    const int l15  = lane & 15;
    const int q8   = (lane >> 4) * 8;
    const int q4   = (lane >> 4) * 4;

    int aRow0 = 0, wRow0 = 0, kStart = 0;
    const unsigned short* Ap = A;
    const unsigned short* Wp = W;
    const int tT = blockIdx.y;
    const int tl = tT & 31;
    int jt = 0;

    if (MODE == 0 || MODE == 1) {
        aRow0 = blockIdx.y * 128;
        wRow0 = blockIdx.x * 128;
    } else if (MODE == 2) {
        jt = tl - 4 + (int)blockIdx.x;
        if (jt < 0) return;
        aRow0 = tT * 128;
        wRow0 = (tT >> 5) * S_LEN + jt * 128;
    } else {                                        // MODE 3
        kStart = (tl < 4) ? (4 - tl) * 128 : 0;
        Ap = A + (size_t)tT * 128 * 640;
        Wp = W + (size_t)((tT >> 5) * H_DIM + blockIdx.x * 128) * S_LEN;
        Wp += (ptrdiff_t)(tl - 4) * 128;
    }

    floatx4 acc[4][4];
#pragma unroll
    for (int i = 0; i < 4; ++i)
#pragma unroll
        for (int j = 0; j < 4; ++j) acc[i][j] = (floatx4)0.0f;

    for (int k0 = kStart; k0 < K; k0 += 32) {
        __syncthreads();
#pragma unroll
        for (int p = 0; p < 2; ++p) {
            const int c = p * 256 + tid;
            const unsigned short* gA = Ap + (size_t)(aRow0 + (c >> 2)) * lda + k0 + (c & 3) * 8;
            const unsigned short* gW = Wp + (size_t)(wRow0 + (c >> 2)) * ldw + k0 + (c & 3) * 8;
            GLOAD_LDS16(gA, (char*)As + (size_t)(p * 256 + w4 * 64) * 16);
            GLOAD_LDS16(gW, (char*)Bs + (size_t)(p * 256 + w4 * 64) * 16);
        }
        __syncthreads();

        short8 af[4], bf[4];
#pragma unroll
        for (int mt = 0; mt < 4; ++mt)
            af[mt] = *(const short8*)(As + (wm * 64 + mt * 16 + l15) * 32 + q8);
#pragma unroll
        for (int nt = 0; nt < 4; ++nt)
            bf[nt] = *(const short8*)(Bs + (wn * 64 + nt * 16 + l15) * 32 + q8);
#pragma unroll
        for (int mt = 0; mt < 4; ++mt)
#pragma unroll
            for (int nt = 0; nt < 4; ++nt)
                acc[mt][nt] = MFMA(af[mt], bf[nt], acc[mt][nt]);
    }

    // ---- epilogue (C/D layout: col=lane&15, row=(lane>>4)*4+r)
#pragma unroll
    for (int nt = 0; nt < 4; ++nt) {
        const int ol = wn * 64 + nt * 16 + l15;            // local col
#pragma unroll
        for (int mt = 0; mt < 4; ++mt) {
#pragma unroll
            for (int r = 0; r < 4; ++r) {
                const int nl = wm * 64 + mt * 16 + q4 + r; // local row
                const float v = acc[mt][nt][r];
                if (MODE == 0) {
                    const int o = wRow0 + ol;
                    if (o < p0)
                        ((unsigned short*)outp)[(size_t)(aRow0 + nl) * ldo + o] = f32_to_bf16_rn(v);
                } else if (MODE == 1) {
                    const int o = wRow0 + ol;              // global x row
                    const int n = aRow0 + nl;              // h
                    ((unsigned short*)outp)[((size_t)(o >> 12) * H_DIM + n) * S_LEN + (o & (S_LEN - 1))] =
                        f32_to_bf16_rn(v);
                } else if (MODE == 2) {
                    const int d = (tl - jt) * 128 + nl - ol;
                    const float pv = (d >= 0) ? v * exp2f((float)d * LOG2G) : 0.0f;
                    ((unsigned short*)outp)[(size_t)tT * (128 * 640) + (size_t)nl * 640 +
                                            (size_t)blockIdx.x * 128 + ol] = f32_to_bf16_rn(pv);
                } else {                                   // MODE 3
                    const int row = tT * 128 + nl;
                    const int col = blockIdx.x * 128 + ol;
                    ((float*)outp)[(size_t)row * H_DIM + col] = v;
                }
            }
        }
    }
}

// ---------------------------------------------------------------- launcher
extern "C" void kernel_launch(void* const* d_in, const int* in_sizes, int n_in,
                              void* d_out, int out_size, void* d_ws, size_t ws_size,
                              hipStream_t stream) {
    (void)in_sizes; (void)n_in; (void)out_size; (void)ws_size;

    const float* x  = (const float*)d_in[0];
    const float* Wq = (const float*)d_in[1];
    const float* bq = (const float*)d_in[2];
    const float* Wk = (const float*)d_in[3];
    const float* bk = (const float*)d_in[4];
    const float* Wv = (const float*)d_in[5];
    float* out = (float*)d_out;

    // workspace layout (bytes, all 16B aligned):
    unsigned short* xtb = (unsigned short*)d_ws;                    // 16384*1056*2 = 34.6 MB
    unsigned short* gb  = xtb + (size_t)NROWS * HP;                 // 34.6 MB
    unsigned short* vtb = gb  + (size_t)NROWS * HP;                 // 16384*1024*2 = 33.6 MB
    unsigned short* pb  = vtb + (size_t)NROWS * H_DIM;              // 128*128*640*2 = 21.0 MB
    unsigned short* wqT = pb  + (size_t)128 * 128 * 640;            // 1152*1024*2
    unsigned short* wkT = wqT + (size_t)WR * H_DIM;
    unsigned short* p1  = wkT + (size_t)WR * H_DIM;                 // 1152*1056*2
    unsigned short* wvb = p1  + (size_t)WR * HP;                    // 1024*1024*2
    // total ~= 133.0 MB

    // stage 0: conversions / transposes
    cvt_x<<<NROWS * 128 / 256, 256, 0, stream>>>(x, xtb);
    fill_pad<<<NROWS * 4 / 256, 256, 0, stream>>>(xtb);
    cvt_bf16<<<H_DIM * H_DIM / 4 / 256, 256, 0, stream>>>(Wv, wvb, H_DIM * H_DIM / 4);
    tr_cvt<<<dim3(8, 36), 256, 0, stream>>>(Wq, bq, wqT);
    tr_cvt<<<dim3(8, 36), 256, 0, stream>>>(Wk, bk, wkT);

    // stage 1: P1 = W~kT . W~qT^T  (1152 x 1152->1056 cols, K=1024)
    gemm128<0><<<dim3(9, 9), 256, 0, stream>>>(wkT, 1024, wqT, 1024, p1, HP, 1024, HP);

    // stage 2: G = x~ . P1^T  (16384 x 1056, K=1056)
    gemm128<0><<<dim3(9, NROWS / 128), 256, 0, stream>>>(xtb, HP, p1, HP, gb, HP, HP, HP);

    // stage 3: Vt = Wv . x~^T scattered to [b][h][s]  (K=1024)
    gemm128<1><<<dim3(NROWS / 128, H_DIM / 128), 256, 0, stream>>>(wvb, 1024, xtb, HP, vtb, 0, 1024, 0);

    // stage 4: Pb = band(G . x~^T) * gamma^d  (5 key slots per q-tile, K=1056)
    gemm128<2><<<dim3(5, NROWS / 128), 256, 0, stream>>>(gb, HP, xtb, HP, pb, 640, HP, 0);

    // stage 5: out = Pb . Vt^T  (banded K up to 640, f32)
    gemm128<3><<<dim3(H_DIM / 128, NROWS / 128), 256, 0, stream>>>(pb, 640, vtb, S_LEN, out, H_DIM, 640, 0);
}

// Round 5
// 352.777 us; speedup vs baseline: 2.1925x; 1.1547x over previous
//
#include <hip/hip_runtime.h>

// Retention, B=4 S=4096 H=1024, gamma=0.96875.
// out[b,i,:] = sum_{j<=i} gamma^(i-j) * (q_i . k_j) * v_j
//
// Pipeline (all bf16 MFMA GEMMs, 128x128 tile, BK=64 double-half staging, XCD-swizzled grids):
//   x~   = [x | 1 | 0pad63]               (16384 x 1088 bf16)
//   W~qT = [Wq^T ; bq ; 0pad]             (1152 x 1024 bf16)   (same for k)
//   P1   = W~kT . W~qT^T                  (1152 x 1088)   P1[h2,h1] = M~[h1,h2]
//   G    = x~ . P1^T = x~ M~              (16384 x 1088)
//   Vt   = (Wv . x~^T) scattered          ([b][h][s] bf16)
//   Pb   = band(G . x~^T) * gamma^d       (128 qtiles x 128 x 640 bf16)
//   out  = Pb . Vt^T (banded K)           (f32)
// Band = 5 key-tiles of 128 => window 512..639; truncated tail < 1e-5 << threshold.

typedef __attribute__((ext_vector_type(8))) short short8;   // 8 bf16 = 4 VGPRs
typedef __attribute__((ext_vector_type(4))) float floatx4;  // MFMA 16x16 C/D

#define MFMA(a, b, c) __builtin_amdgcn_mfma_f32_16x16x32_bf16((a), (b), (c), 0, 0, 0)

#define B_SZ   4
#define S_LEN  4096
#define H_DIM  1024
#define NROWS  (B_SZ * S_LEN)          // 16384
#define HP     1088                    // padded H+1 (17*64)
#define WR     1152                    // padded weight rows (9*128)
#define LOG2G  (-0.045803690f)         // log2(0.96875)

__device__ __forceinline__ unsigned short f32_to_bf16_rn(float f) {
    unsigned int u = __float_as_uint(f);
    u += 0x7FFFu + ((u >> 16) & 1u);   // round-to-nearest-even
    return (unsigned short)(u >> 16);
}

#define GLOAD_LDS16(gptr, lptr)                                                        \
    __builtin_amdgcn_global_load_lds((__attribute__((address_space(1))) void*)(gptr),  \
                                     (__attribute__((address_space(3))) void*)(lptr),  \
                                     16, 0, 0)

// ---------------------------------------------------------------- cvt f32->bf16 (contiguous)
__global__ __launch_bounds__(256) void cvt_bf16(const float* __restrict__ src,
                                                unsigned short* __restrict__ dst, int n4) {
    int i = blockIdx.x * 256 + threadIdx.x;
    if (i >= n4) return;
    float4 v = ((const float4*)src)[i];
    ushort4 o;
    o.x = f32_to_bf16_rn(v.x);
    o.y = f32_to_bf16_rn(v.y);
    o.z = f32_to_bf16_rn(v.z);
    o.w = f32_to_bf16_rn(v.w);
    ((ushort4*)dst)[i] = o;
}

// ---------------------------------------------------------------- cvt x -> x~ rows of HP
__global__ __launch_bounds__(256) void cvt_x(const float* __restrict__ src,
                                             unsigned short* __restrict__ dst) {
    int idx = blockIdx.x * 256 + threadIdx.x;     // 16384*128 chunks of 8
    int row = idx >> 7, c8 = (idx & 127) * 8;
    const float4* s = (const float4*)(src + (size_t)row * H_DIM + c8);
    float4 a = s[0], b = s[1];
    ushort4 o0, o1;
    o0.x = f32_to_bf16_rn(a.x); o0.y = f32_to_bf16_rn(a.y);
    o0.z = f32_to_bf16_rn(a.z); o0.w = f32_to_bf16_rn(a.w);
    o1.x = f32_to_bf16_rn(b.x); o1.y = f32_to_bf16_rn(b.y);
    o1.z = f32_to_bf16_rn(b.z); o1.w = f32_to_bf16_rn(b.w);
    ushort4* d = (ushort4*)(dst + (size_t)row * HP + c8);
    d[0] = o0; d[1] = o1;
}

// cols 1024..1087 of x~: 1.0 at col 1024, zeros elsewhere
__global__ __launch_bounds__(256) void fill_pad(unsigned short* __restrict__ dst) {
    int idx = blockIdx.x * 256 + threadIdx.x;     // 16384*8 chunks of 8
    int row = idx >> 3, c = idx & 7;
    uint4 v; v.x = (c == 0) ? 0x00003F80u : 0u; v.y = 0u; v.z = 0u; v.w = 0u;
    *(uint4*)(dst + (size_t)row * HP + 1024 + c * 8) = v;
}

// ---------------------------------------------------------------- W (f32) + bias -> [W^T ; bias ; 0] bf16, 1152x1024
__global__ __launch_bounds__(256) void tr_cvt(const float* __restrict__ Wsrc,
                                              const float* __restrict__ bias,
                                              unsigned short* __restrict__ dst) {
    const int tid = threadIdx.x;
    const int bx = blockIdx.x, by = blockIdx.y;
    if (by >= 32) {                                // rows 1024..1151: bias row + zeros
        if (bx != 0) return;
        const int h0 = by * 32;
#pragma unroll
        for (int i = 0; i < 128; ++i) {
            int idx = i * 256 + tid;               // 32*1024
            int r = idx >> 10, cc = idx & 1023;
            int h = h0 + r;
            float v = (h == 1024) ? bias[cc] : 0.0f;
            dst[(size_t)h * 1024 + cc] = f32_to_bf16_rn(v);
        }
        return;
    }
    __shared__ float Lt[128][33];
    const int w0 = bx * 128, h0 = by * 32;
#pragma unroll
    for (int i = 0; i < 16; ++i) {
        int idx = i * 256 + tid;
        int r = idx >> 5, cc = idx & 31;
        Lt[r][cc] = Wsrc[(size_t)(w0 + r) * 1024 + h0 + cc];
    }
    __syncthreads();
#pragma unroll
    for (int i = 0; i < 16; ++i) {
        int idx = i * 256 + tid;
        int hh = idx >> 7, ww = idx & 127;
        dst[(size_t)(h0 + hh) * 1024 + w0 + ww] = f32_to_bf16_rn(Lt[ww][hh]);
    }
}

// ---------------------------------------------------------------- generic 128x128 MFMA GEMM
// C[n,o] = sum_k A[n,k]*W[o,k].  BK=64 as two 32-halves (32 KB LDS), 2 barriers / 64K.
// Staging per 32-half: 512 chunks of 16B, two passes of 256 threads.
// SWZ: 1-D grid; g=bid&7 selects XCD-local group of 16 "by" tiles x nx "bx" tiles.
// MODE 0: bf16 row-major store (col-clip p0)   MODE 1: Vt scatter (by=xtile, bx=htile)
// MODE 2: decay epilogue -> Pb band            MODE 3: banded-K, f32 store
template <int MODE, int SWZ>
__global__ __launch_bounds__(256) void gemm128(const unsigned short* __restrict__ A, int lda,
                                               const unsigned short* __restrict__ W, int ldw,
                                               void* __restrict__ outp, int ldo, int K, int p0,
                                               int nx) {
    __shared__ unsigned short As[2][128 * 32];
    __shared__ unsigned short Bs[2][128 * 32];

    const int tid  = threadIdx.x;
    const int lane = tid & 63;
    const int w4   = tid >> 6;
    const int wm   = w4 >> 1, wn = w4 & 1;
    const int l15  = lane & 15;
    const int q8   = (lane >> 4) * 8;
    const int q4   = (lane >> 4) * 4;

    int bx, by;
    if (SWZ) {
        const int bid = blockIdx.x;
        const int g = bid & 7, j = bid >> 3;
        by = g * 16 + j / nx;
        bx = j % nx;
    } else {
        bx = blockIdx.x; by = blockIdx.y;
    }

    int aRow0 = 0, wRow0 = 0, kStart = 0;
    const unsigned short* Ap = A;
    const unsigned short* Wp = W;
    const int tT = by;
    const int tl = tT & 31;
    int jt = 0;

    if (MODE == 0) {
        aRow0 = by * 128; wRow0 = bx * 128;
    } else if (MODE == 1) {
        aRow0 = bx * 128; wRow0 = by * 128;       // bx=h-tile, by=x-row-tile (localized)
    } else if (MODE == 2) {
        jt = tl - 4 + bx;
        if (jt < 0) return;
        aRow0 = tT * 128;
        wRow0 = (tT >> 5) * S_LEN + jt * 128;
    } else {                                       // MODE 3
        kStart = (tl < 4) ? (4 - tl) * 128 : 0;
        Ap = A + (size_t)tT * 128 * 640;
        Wp = W + (size_t)((tT >> 5) * H_DIM + bx * 128) * S_LEN + (ptrdiff_t)(tl - 4) * 128;
    }

    floatx4 acc[4][4];
#pragma unroll
    for (int i = 0; i < 4; ++i)
#pragma unroll
        for (int j = 0; j < 4; ++j) acc[i][j] = (floatx4)0.0f;

    for (int k0 = kStart; k0 < K; k0 += 64) {
        __syncthreads();
#pragma unroll
        for (int p = 0; p < 2; ++p) {
            const int c = p * 256 + tid;           // chunk id in [0,512): row=c>>2, ch=c&3
            const unsigned short* gA = Ap + (size_t)(aRow0 + (c >> 2)) * lda + k0 + (c & 3) * 8;
            const unsigned short* gW = Wp + (size_t)(wRow0 + (c >> 2)) * ldw + k0 + (c & 3) * 8;
            char* dA0 = (char*)&As[0][0] + (size_t)(p * 256 + w4 * 64) * 16;
            char* dA1 = (char*)&As[1][0] + (size_t)(p * 256 + w4 * 64) * 16;
            char* dB0 = (char*)&Bs[0][0] + (size_t)(p * 256 + w4 * 64) * 16;
            char* dB1 = (char*)&Bs[1][0] + (size_t)(p * 256 + w4 * 64) * 16;
            GLOAD_LDS16(gA,      dA0);
            GLOAD_LDS16(gA + 32, dA1);
            GLOAD_LDS16(gW,      dB0);
            GLOAD_LDS16(gW + 32, dB1);
        }
        __syncthreads();

#pragma unroll
        for (int h = 0; h < 2; ++h) {
            short8 af[4], bf[4];
#pragma unroll
            for (int mt = 0; mt < 4; ++mt)
                af[mt] = *(const short8*)(&As[h][0] + (wm * 64 + mt * 16 + l15) * 32 + q8);
#pragma unroll
            for (int nt = 0; nt < 4; ++nt)
                bf[nt] = *(const short8*)(&Bs[h][0] + (wn * 64 + nt * 16 + l15) * 32 + q8);
#pragma unroll
            for (int mt = 0; mt < 4; ++mt)
#pragma unroll
                for (int nt = 0; nt < 4; ++nt)
                    acc[mt][nt] = MFMA(af[mt], bf[nt], acc[mt][nt]);
        }
    }

    // ---- epilogue (C/D layout: col=lane&15, row=(lane>>4)*4+r)
#pragma unroll
    for (int nt = 0; nt < 4; ++nt) {
        const int ol = wn * 64 + nt * 16 + l15;
#pragma unroll
        for (int mt = 0; mt < 4; ++mt) {
#pragma unroll
            for (int r = 0; r < 4; ++r) {
                const int nl = wm * 64 + mt * 16 + q4 + r;
                const float v = acc[mt][nt][r];
                if (MODE == 0) {
                    const int o = wRow0 + ol;
                    if (o < p0)
                        ((unsigned short*)outp)[(size_t)(aRow0 + nl) * ldo + o] = f32_to_bf16_rn(v);
                } else if (MODE == 1) {
                    const int s = wRow0 + ol;              // global x row
                    const int hh = aRow0 + nl;             // h
                    ((unsigned short*)outp)[((size_t)(s >> 12) * H_DIM + hh) * S_LEN + (s & (S_LEN - 1))] =
                        f32_to_bf16_rn(v);
                } else if (MODE == 2) {
                    const int d = (tl - jt) * 128 + nl - ol;
                    const float pv = (d >= 0) ? v * exp2f((float)d * LOG2G) : 0.0f;
                    ((unsigned short*)outp)[(size_t)tT * (128 * 640) + (size_t)nl * 640 +
                                            (size_t)bx * 128 + ol] = f32_to_bf16_rn(pv);
                } else {                                   // MODE 3
                    ((float*)outp)[(size_t)(tT * 128 + nl) * H_DIM + bx * 128 + ol] = v;
                }
            }
        }
    }
}

// ---------------------------------------------------------------- launcher
extern "C" void kernel_launch(void* const* d_in, const int* in_sizes, int n_in,
                              void* d_out, int out_size, void* d_ws, size_t ws_size,
                              hipStream_t stream) {
    (void)in_sizes; (void)n_in; (void)out_size; (void)ws_size;

    const float* x  = (const float*)d_in[0];
    const float* Wq = (const float*)d_in[1];
    const float* bq = (const float*)d_in[2];
    const float* Wk = (const float*)d_in[3];
    const float* bk = (const float*)d_in[4];
    const float* Wv = (const float*)d_in[5];
    float* out = (float*)d_out;

    unsigned short* xtb = (unsigned short*)d_ws;                    // 16384*1088*2 = 35.7 MB
    unsigned short* gb  = xtb + (size_t)NROWS * HP;                 // 35.7 MB
    unsigned short* vtb = gb  + (size_t)NROWS * HP;                 // 33.6 MB
    unsigned short* pb  = vtb + (size_t)NROWS * H_DIM;              // 21.0 MB
    unsigned short* wqT = pb  + (size_t)128 * 128 * 640;            // 2.36 MB
    unsigned short* wkT = wqT + (size_t)WR * H_DIM;                 // 2.36 MB
    unsigned short* p1  = wkT + (size_t)WR * H_DIM;                 // 1152*1088*2 = 2.5 MB
    unsigned short* wvb = p1  + (size_t)WR * HP;                    // 2.1 MB
    // total ~= 135 MB

    cvt_x<<<NROWS * 128 / 256, 256, 0, stream>>>(x, xtb);
    fill_pad<<<NROWS * 8 / 256, 256, 0, stream>>>(xtb);
    cvt_bf16<<<H_DIM * H_DIM / 4 / 256, 256, 0, stream>>>(Wv, wvb, H_DIM * H_DIM / 4);
    tr_cvt<<<dim3(8, 36), 256, 0, stream>>>(Wq, bq, wqT);
    tr_cvt<<<dim3(8, 36), 256, 0, stream>>>(Wk, bk, wkT);

    // P1 = W~kT . W~qT^T  (1152 x 1088, K=1024) — tiny, unswizzled
    gemm128<0, 0><<<dim3(9, 9), 256, 0, stream>>>(wkT, 1024, wqT, 1024, p1, HP, 1024, HP, 0);

    // G = x~ . P1^T  (16384 x 1088, K=1088)
    gemm128<0, 1><<<9 * 128, 256, 0, stream>>>(xtb, HP, p1, HP, gb, HP, HP, HP, 9);

    // Vt = Wv . x~^T scattered to [b][h][s]  (K=1024); localized on x-row-tiles
    gemm128<1, 1><<<8 * 128, 256, 0, stream>>>(wvb, 1024, xtb, HP, vtb, 0, 1024, 0, 8);

    // Pb = band(G . x~^T) * gamma^d  (5 slots per q-tile, K=1088)
    gemm128<2, 1><<<5 * 128, 256, 0, stream>>>(gb, HP, xtb, HP, pb, 640, HP, 0, 5);

    // out = Pb . Vt^T  (banded K<=640, f32)
    gemm128<3, 1><<<8 * 128, 256, 0, stream>>>(pb, 640, vtb, S_LEN, out, H_DIM, 640, 0, 8);
}